// Round 1
// baseline (6999.648 us; speedup 1.0000x reference)
//
#include <hip/hip_runtime.h>
#include <stdint.h>

// ---------------- problem constants ----------------
#define T_STEPS 512
#define BATCH   128
#define HDIM    512
#define H3      1536
#define KK      1024            // combined K = 2*HDIM  ([x | h] @ [Wi ; Wh])
#define NGROUPS 8               // batch groups (independent recurrences)
#define BT      16              // batch rows per group  (BATCH/NGROUPS)
#define NCOLBLK 32              // column blocks per group
#define CPB     16              // h-columns per block   (HDIM/NCOLBLK)
#define NBLOCKS (NGROUPS*NCOLBLK)   // 256 == #CUs -> all co-resident
#define THREADS 512
#define AS      1032            // A-tile LDS row stride in shorts (1024 + 8 pad)
                                // -> stride/8 = 129 (odd): ds_read_b128 lanes spread
                                //    uniformly over the 8 bank-groups (optimal)

// ---------------- workspace layout (bytes) ----------------
#define OFF_INSB   0u                    // bf16 ins [T*B][H]      64 MiB
#define OFF_WT     67108864u             // bf16 WT  [1536][1024]   3 MiB (row n = [Wi col n | Wh col n])
#define OFF_HBUF0  70254592u             // bf16 h ping  [B][H]   128 KiB
#define OFF_HBUF1  70385664u             // bf16 h pong  [B][H]   128 KiB
#define OFF_RMASK  70516736u             // u8 canonical resets    64 KiB
#define OFF_FLAG   70582272u             // int detector flag (+pad)
#define OFF_CNT    70582528u             // int cnt[8][513] barrier counters
#define CNT_BYTES  (NGROUPS*(T_STEPS+1)*4)

typedef __attribute__((ext_vector_type(8))) short  short8;
typedef __attribute__((ext_vector_type(4))) float  f32x4;

__device__ __forceinline__ unsigned short f2bf(float f) {
    unsigned int u = __float_as_uint(f);
    unsigned int r = (u + 0x7FFFu + ((u >> 16) & 1u)) >> 16;
    return (unsigned short)r;
}
__device__ __forceinline__ float sigmoidf_(float x) { return 1.0f / (1.0f + __expf(-x)); }
__device__ __forceinline__ float tanhf_(float x)    { return 1.0f - 2.0f / (1.0f + __expf(2.0f * x)); }

// ---------------- resets dtype detector ----------------
// bool storage unknown: 1-byte (np.bool_), int32{0,1}, or float32{0,1.0}.
// Read first 64KB as u32 words (safe in every world). 4-byte-per-elem worlds
// only contain {0, 1, 0x3F800000}; packed-byte world almost surely doesn't.
__global__ void k_detect(const unsigned int* __restrict__ r32, int* __restrict__ flag) {
    unsigned int bad = 0;
    for (int i = threadIdx.x; i < 16384; i += 256) {
        unsigned int w = r32[i];
        if (w != 0u && w != 1u && w != 0x3F800000u) bad = 1u;
    }
    if (__any(bad)) { if ((threadIdx.x & 63) == 0) atomicOr(flag, 1); }
}

__global__ void k_canon(const unsigned char* __restrict__ r8,
                        const unsigned int* __restrict__ r32,
                        const int* __restrict__ flag,
                        unsigned char* __restrict__ rmask) {
    int i = blockIdx.x * 256 + threadIdx.x;           // i < 65536
    if (*flag) rmask[i] = r8[i] ? 1 : 0;              // packed-byte bools
    else       rmask[i] = r32[i] ? 1 : 0;             // int32 or float32 bit pattern
}

// ---------------- fp32 -> bf16 bulk convert of ins ----------------
__global__ void k_cvt_ins(const float* __restrict__ in, unsigned short* __restrict__ out) {
    size_t i = ((size_t)blockIdx.x * 256 + threadIdx.x) * 8;
    const f32x4* p = (const f32x4*)(in + i);
    f32x4 a = p[0], b = p[1];
    union { short8 v; unsigned short s[8]; } o;
    o.s[0] = f2bf(a[0]); o.s[1] = f2bf(a[1]); o.s[2] = f2bf(a[2]); o.s[3] = f2bf(a[3]);
    o.s[4] = f2bf(b[0]); o.s[5] = f2bf(b[1]); o.s[6] = f2bf(b[2]); o.s[7] = f2bf(b[3]);
    *(short8*)(out + i) = o.v;
}

// ---------------- build WT[n][k] = bf16( k<512 ? Wi[k][n] : Wh[k-512][n] ) ----------------
__global__ void k_build_wt(const float* __restrict__ Wi, const float* __restrict__ Wh,
                           unsigned short* __restrict__ WT) {
    int gid = blockIdx.x * 256 + threadIdx.x;         // over 1536*1024
    int n = gid >> 10, k = gid & 1023;
    float v = (k < 512) ? Wi[(size_t)k * H3 + n] : Wh[(size_t)(k - 512) * H3 + n];
    WT[gid] = f2bf(v);
}

// ---------------- persistent GRU recurrence ----------------
// grid = 256 blocks (= #CUs), 512 threads (8 waves). Block (g, cb):
//   batch rows g*16..g*16+15, h-columns c0..c0+15.
// Wave w owns K range [w*128, w*128+128): waves 0-3 = x@Wi half, 4-7 = h@Wh half.
// Per wave 12 B-fragments (3 gate n-tiles x 4 k-steps) held in registers forever.
__global__ __launch_bounds__(THREADS, 1)
void rnn_persist(const float* __restrict__ h0,
                 const float* __restrict__ bi,
                 const float* __restrict__ bhn,
                 const unsigned char* __restrict__ rmask,
                 const unsigned short* __restrict__ insB,
                 const unsigned short* __restrict__ WT,
                 unsigned short* __restrict__ hbuf0,
                 unsigned short* __restrict__ hbuf1,
                 int* __restrict__ cnt,
                 float* __restrict__ ys) {
    __shared__ unsigned short a_lds[BT * AS];     // 33,024 B: [16 rows][1024 k] (+pad): x half then h half
    __shared__ float part[8 * 768];               // 24,576 B: per-wave partials [w][n48][m16]
    __shared__ float h_own[BT * 17];              //  1,088 B: fp32 carried state (block's own 16x16 patch)
    __shared__ float bi_lds[48];
    __shared__ float bhn_lds[16];

    const int blk  = blockIdx.x;
    const int g    = blk >> 5;                    // batch group
    const int cb   = blk & 31;                    // column block
    const int c0   = cb * CPB;
    const int tid  = threadIdx.x;
    const int w    = tid >> 6;
    const int lane = tid & 63;
    const int quad = lane >> 4;
    const int l16  = lane & 15;

    // ---- load B fragments into registers (once) ----
    short8 bfrag[3][4];
#pragma unroll
    for (int tn = 0; tn < 3; ++tn) {
        int row = tn * HDIM + c0 + l16;           // WT row = gate column
#pragma unroll
        for (int ks = 0; ks < 4; ++ks) {
            int k = w * 128 + ks * 32 + quad * 8;
            bfrag[tn][ks] = *reinterpret_cast<const short8*>(WT + (size_t)row * KK + k);
        }
    }

    // ---- biases to LDS ----
    if (tid < 48)      { int gate = tid >> 4, u = tid & 15; bi_lds[tid] = bi[gate * HDIM + c0 + u]; }
    else if (tid < 64) { bhn_lds[tid - 48] = bhn[c0 + (tid - 48)]; }

    // ---- init carried state + h ping buffer (union of all blocks covers [B][H]) ----
    if (tid < 256) {
        int m = tid & 15, u = tid >> 4;
        float v = h0[(size_t)(g * BT + m) * HDIM + c0 + u];
        h_own[m * 17 + u] = v;
        hbuf0[(size_t)(g * BT + m) * HDIM + c0 + u] = f2bf(v);
    }

    // ---- prefetch x_0 into LDS x-half ----
    {
        const unsigned short* src = insB + (size_t)g * BT * HDIM;   // t=0
        for (int c = tid; c < 1024; c += THREADS) {
            int row = c >> 6, kc = c & 63;
            short8 v = *reinterpret_cast<const short8*>(src + row * HDIM + kc * 8);
            *reinterpret_cast<short8*>(&a_lds[row * AS + kc * 8]) = v;
        }
    }
    __syncthreads();

    int* mycnt = cnt + g * (T_STEPS + 1);
    if (tid == 0)
        __hip_atomic_fetch_add(&mycnt[0], 1, __ATOMIC_RELEASE, __HIP_MEMORY_SCOPE_AGENT);

    for (int t = 0; t < T_STEPS; ++t) {
        // ---- phase A: thread0 spins on group barrier; waves 4-7 prefetch x_{t+1} to regs ----
        short8 xr[4];
        if (w >= 4 && t + 1 < T_STEPS) {
            const unsigned short* src = insB + (size_t)(t + 1) * BATCH * HDIM + (size_t)g * BT * HDIM;
            int base = (tid - 256) * 4;
#pragma unroll
            for (int i = 0; i < 4; ++i) {
                int c = base + i; int row = c >> 6, kc = c & 63;
                xr[i] = *reinterpret_cast<const short8*>(src + row * HDIM + kc * 8);
            }
        }
        unsigned char myrst = 0;
        if (tid < 256) myrst = rmask[t * BATCH + g * BT + (tid & 15)];
        if (tid == 0) {
            int spin = 0;
            while (__hip_atomic_load(&mycnt[t], __ATOMIC_ACQUIRE, __HIP_MEMORY_SCOPE_AGENT) < NCOLBLK) {
                __builtin_amdgcn_s_sleep(1);
                if (++spin > (1 << 17)) break;        // failsafe vs hang (never hit when co-resident)
            }
        }
        __syncthreads();

        // ---- phase B: waves 0-3 stage h_t (reset-masked) into LDS h-half ----
        if (w < 4) {
            const unsigned short* hb = (t & 1) ? hbuf1 : hbuf0;
            int row = tid >> 4;                       // 4 consecutive 16B chunks share a row
            unsigned char rst = rmask[t * BATCH + g * BT + row];
            int base = tid * 4;
#pragma unroll
            for (int i = 0; i < 4; ++i) {
                int c = base + i; int kc = c & 63;
                short8 v = *reinterpret_cast<const short8*>(hb + (size_t)(g * BT + row) * HDIM + kc * 8);
                if (rst) v = short8(0);
                *reinterpret_cast<short8*>(&a_lds[row * AS + HDIM + kc * 8]) = v;
            }
        }
        __syncthreads();

        // ---- phase C: MFMA  acc[tn] += A[16 x 128_w] * B_w[128 x 16] ----
        f32x4 acc[3] = {f32x4(0.f), f32x4(0.f), f32x4(0.f)};
#pragma unroll
        for (int ks = 0; ks < 4; ++ks) {
            short8 a = *reinterpret_cast<const short8*>(
                &a_lds[l16 * AS + w * 128 + ks * 32 + quad * 8]);
            acc[0] = __builtin_amdgcn_mfma_f32_16x16x32_bf16(a, bfrag[0][ks], acc[0], 0, 0, 0);
            acc[1] = __builtin_amdgcn_mfma_f32_16x16x32_bf16(a, bfrag[1][ks], acc[1], 0, 0, 0);
            acc[2] = __builtin_amdgcn_mfma_f32_16x16x32_bf16(a, bfrag[2][ks], acc[2], 0, 0, 0);
        }
#pragma unroll
        for (int tn = 0; tn < 3; ++tn)
            *reinterpret_cast<f32x4*>(&part[w * 768 + (tn * 16 + l16) * 16 + quad * 4]) = acc[tn];
        __syncthreads();

        // ---- phase D: tid<256 reduce K-split partials + gates; tid>=256 write x_{t+1} to LDS ----
        if (tid >= 256) {
            if (t + 1 < T_STEPS) {
                int base = (tid - 256) * 4;
#pragma unroll
                for (int i = 0; i < 4; ++i) {
                    int c = base + i; int row = c >> 6, kc = c & 63;
                    *reinterpret_cast<short8*>(&a_lds[row * AS + kc * 8]) = xr[i];
                }
            }
        } else {
            int m = tid & 15, u = tid >> 4;           // m-fast: conflict-free part[] reads
            float rs = 0.f, zs = 0.f, ni = 0.f, nh = 0.f;
#pragma unroll
            for (int ww = 0; ww < 8; ++ww) {
                rs += part[ww * 768 + u * 16 + m];
                zs += part[ww * 768 + (16 + u) * 16 + m];
                float p = part[ww * 768 + (32 + u) * 16 + m];
                if (ww < 4) ni += p; else nh += p;    // Wi-half vs Wh-half of the n gate
            }
            float r = sigmoidf_(rs + bi_lds[u]);
            float z = sigmoidf_(zs + bi_lds[16 + u]);
            float n = tanhf_(ni + bi_lds[32 + u] + r * (nh + bhn_lds[u]));
            float hp = myrst ? 0.f : h_own[m * 17 + u];
            h_own[m * 17 + u] = (1.f - z) * n + z * hp;
        }
        __syncthreads();

        // ---- phase E: coalesced output writes (u-fast) ----
        if (tid < 256) {
            int u = tid & 15, m = tid >> 4;
            float v = h_own[m * 17 + u];
            ys[((size_t)t * BATCH + g * BT + m) * HDIM + c0 + u] = v;
            unsigned short* hbn = ((t + 1) & 1) ? hbuf1 : hbuf0;
            hbn[(size_t)(g * BT + m) * HDIM + c0 + u] = f2bf(v);
        }
        __syncthreads();
        if (tid == 0)
            __hip_atomic_fetch_add(&mycnt[t + 1], 1, __ATOMIC_RELEASE, __HIP_MEMORY_SCOPE_AGENT);
    }
}

extern "C" void kernel_launch(void* const* d_in, const int* in_sizes, int n_in,
                              void* d_out, int out_size, void* d_ws, size_t ws_size,
                              hipStream_t stream) {
    const float* ins    = (const float*)d_in[0];
    const void*  resets = d_in[1];
    const float* h0     = (const float*)d_in[2];
    const float* Wi     = (const float*)d_in[3];
    const float* Wh     = (const float*)d_in[4];
    const float* bi     = (const float*)d_in[5];
    const float* bhn    = (const float*)d_in[6];
    float* ys = (float*)d_out;
    char* ws = (char*)d_ws;

    unsigned short* insB  = (unsigned short*)(ws + OFF_INSB);
    unsigned short* WT    = (unsigned short*)(ws + OFF_WT);
    unsigned short* hbuf0 = (unsigned short*)(ws + OFF_HBUF0);
    unsigned short* hbuf1 = (unsigned short*)(ws + OFF_HBUF1);
    unsigned char*  rmask = (unsigned char*)(ws + OFF_RMASK);
    int*            flag  = (int*)(ws + OFF_FLAG);
    int*            cnt   = (int*)(ws + OFF_CNT);

    // counters + flag are re-poisoned 0xAA before every call -> must zero each launch
    hipMemsetAsync(ws + OFF_FLAG, 0, 256 + CNT_BYTES, stream);

    k_detect<<<1, 256, 0, stream>>>((const unsigned int*)resets, flag);
    k_canon<<<256, 256, 0, stream>>>((const unsigned char*)resets, (const unsigned int*)resets, flag, rmask);
    k_cvt_ins<<<16384, 256, 0, stream>>>(ins, insB);
    k_build_wt<<<6144, 256, 0, stream>>>(Wi, Wh, WT);
    rnn_persist<<<NBLOCKS, THREADS, 0, stream>>>(h0, bi, bhn, rmask, insB, WT, hbuf0, hbuf1, cnt, ys);
}

// Round 3
// 2639.823 us; speedup vs baseline: 2.6516x; 2.6516x over previous
//
#include <hip/hip_runtime.h>
#include <stdint.h>

// ---------------- problem constants ----------------
#define T_STEPS 512
#define BATCH   128
#define HDIM    512
#define H3      1536
#define KK      1024            // combined K = 2*HDIM  ([x | h] @ [Wi ; Wh])
#define NGROUPS 8               // batch groups (independent recurrences)
#define BT      16              // batch rows per group  (BATCH/NGROUPS)
#define NCOLBLK 32              // column blocks per group
#define CPB     16              // h-columns per block   (HDIM/NCOLBLK)
#define NBLOCKS (NGROUPS*NCOLBLK)   // 256 == #CUs -> all co-resident
#define THREADS 512

// ---------------- workspace layout (bytes) ----------------
#define OFF_INSB   0u                    // bf16 ins [T*B][H]      64 MiB
#define OFF_WT     67108864u             // bf16 WT  [1536][1024]   3 MiB
#define OFF_HBUF0  70254592u             // bf16 h ping  [B][H]   128 KiB
#define OFF_HBUF1  70385664u             // bf16 h pong  [B][H]   128 KiB
#define OFF_RMASK  70516736u             // u8 canonical resets    64 KiB
#define OFF_FLAG   70582272u             // int detector flag (+pad)
#define OFF_CNT    70582528u             // int flags[8][32] publish tags (zeroed each launch)
#define CNT_BYTES  (NGROUPS*(T_STEPS+1)*4)

typedef __attribute__((ext_vector_type(8))) short  short8;
typedef __attribute__((ext_vector_type(4))) float  f32x4;

__device__ __forceinline__ unsigned short f2bf(float f) {
    unsigned int u = __float_as_uint(f);
    unsigned int r = (u + 0x7FFFu + ((u >> 16) & 1u)) >> 16;
    return (unsigned short)r;
}
__device__ __forceinline__ float sigmoidf_(float x) { return 1.0f / (1.0f + __expf(-x)); }
__device__ __forceinline__ float tanhf_(float x)    { return 1.0f - 2.0f / (1.0f + __expf(2.0f * x)); }

// ---------------- resets dtype detector (unchanged, known-good) ----------------
__global__ void k_detect(const unsigned int* __restrict__ r32, int* __restrict__ flag) {
    unsigned int bad = 0;
    for (int i = threadIdx.x; i < 16384; i += 256) {
        unsigned int w = r32[i];
        if (w != 0u && w != 1u && w != 0x3F800000u) bad = 1u;
    }
    if (__any(bad)) { if ((threadIdx.x & 63) == 0) atomicOr(flag, 1); }
}

__global__ void k_canon(const unsigned char* __restrict__ r8,
                        const unsigned int* __restrict__ r32,
                        const int* __restrict__ flag,
                        unsigned char* __restrict__ rmask) {
    int i = blockIdx.x * 256 + threadIdx.x;
    if (*flag) rmask[i] = r8[i] ? 1 : 0;
    else       rmask[i] = r32[i] ? 1 : 0;
}

__global__ void k_cvt_ins(const float* __restrict__ in, unsigned short* __restrict__ out) {
    size_t i = ((size_t)blockIdx.x * 256 + threadIdx.x) * 8;
    const f32x4* p = (const f32x4*)(in + i);
    f32x4 a = p[0], b = p[1];
    union { short8 v; unsigned short s[8]; } o;
    o.s[0] = f2bf(a[0]); o.s[1] = f2bf(a[1]); o.s[2] = f2bf(a[2]); o.s[3] = f2bf(a[3]);
    o.s[4] = f2bf(b[0]); o.s[5] = f2bf(b[1]); o.s[6] = f2bf(b[2]); o.s[7] = f2bf(b[3]);
    *(short8*)(out + i) = o.v;
}

__global__ void k_build_wt(const float* __restrict__ Wi, const float* __restrict__ Wh,
                           unsigned short* __restrict__ WT) {
    int gid = blockIdx.x * 256 + threadIdx.x;
    int n = gid >> 10, k = gid & 1023;
    float v = (k < 512) ? Wi[(size_t)k * H3 + n] : Wh[(size_t)(k - 512) * H3 + n];
    WT[gid] = f2bf(v);
}

// ---------------- persistent GRU recurrence, v3 ----------------
// v2 + fix: reference computes h = where(reset,0,h) BEFORE gh = h@Wh. v2 fed
// the UNMASKED h into the MFMA (reset applied only to the z*h leak term) ->
// absmax 1.08. v3: waves 4-7 load rmask[row l16] (issued before the spin) and
// zero their h A-fragments when set. Sync protocol unchanged (verified live:
// no failsafe-timeout signature in v2's 3s wall time).
__global__ __launch_bounds__(THREADS, 2)
void rnn_persist(const float* __restrict__ h0,
                 const float* __restrict__ bi,
                 const float* __restrict__ bhn,
                 const unsigned char* __restrict__ rmask,
                 const unsigned short* __restrict__ insB,
                 const unsigned short* __restrict__ WT,
                 unsigned short* __restrict__ hbuf0,
                 unsigned short* __restrict__ hbuf1,
                 int* __restrict__ flagbase,
                 float* __restrict__ ys) {
    __shared__ float part[8 * 768];               // [wave][n48][m16] fp32 partials
    __shared__ float bi_lds[48];
    __shared__ float bhn_lds[16];

    const int blk  = blockIdx.x;
    const int g    = blk & 7;                     // group -> same XCD (locality only)
    const int cb   = blk >> 3;                    // column block 0..31
    const int c0   = cb * CPB;
    const int tid  = threadIdx.x;
    const int w    = tid >> 6;
    const int lane = tid & 63;
    const int quad = lane >> 4;
    const int l16  = lane & 15;

    int* flags = flagbase + g * 32;

    // ---- B fragments into registers (once): 48 VGPRs/lane ----
    short8 bfrag[3][4];
#pragma unroll
    for (int tn = 0; tn < 3; ++tn) {
        int row = tn * HDIM + c0 + l16;
#pragma unroll
        for (int ks = 0; ks < 4; ++ks) {
            int k = w * 128 + ks * 32 + quad * 8;
            bfrag[tn][ks] = *reinterpret_cast<const short8*>(WT + (size_t)row * KK + k);
        }
    }

    // ---- biases ----
    if (tid < 48)      { bi_lds[tid] = bi[(tid >> 4) * HDIM + c0 + (tid & 15)]; }
    else if (tid < 64) { bhn_lds[tid - 48] = bhn[c0 + (tid - 48)]; }

    // ---- init: carried h in registers; publish h_0 patch; flag = 1 ----
    float h_prev = 0.f;
    if (tid < 256) {
        int m = tid & 15, u = tid >> 4;
        h_prev = h0[(size_t)(g * BT + m) * HDIM + c0 + u];
        __hip_atomic_store(&hbuf0[(size_t)(g * BT + m) * HDIM + c0 + u], f2bf(h_prev),
                           __ATOMIC_RELAXED, __HIP_MEMORY_SCOPE_AGENT);
    }
    asm volatile("s_waitcnt vmcnt(0)" ::: "memory");
    __syncthreads();
    if (tid == 0)
        __hip_atomic_store(&flags[cb], 1, __ATOMIC_RELAXED, __HIP_MEMORY_SCOPE_AGENT);

    // ---- prefetch x_0 A-fragments (waves 0-3 only) ----
    short8 xa[4];
    if (w < 4) {
        const unsigned short* src = insB + (size_t)(g * BT + l16) * HDIM;
#pragma unroll
        for (int ks = 0; ks < 4; ++ks)
            xa[ks] = *reinterpret_cast<const short8*>(src + w * 128 + ks * 32 + quad * 8);
    }

    for (int t = 0; t < T_STEPS; ++t) {
        f32x4 acc[3] = {f32x4(0.f), f32x4(0.f), f32x4(0.f)};
        unsigned char myrst = 0;

        if (w < 4) {
            // x-half: no dependency on other blocks -> runs during their publish
            myrst = rmask[t * BATCH + g * BT + (tid & 15)];
#pragma unroll
            for (int ks = 0; ks < 4; ++ks) {
                acc[0] = __builtin_amdgcn_mfma_f32_16x16x32_bf16(xa[ks], bfrag[0][ks], acc[0], 0, 0, 0);
                acc[1] = __builtin_amdgcn_mfma_f32_16x16x32_bf16(xa[ks], bfrag[1][ks], acc[1], 0, 0, 0);
                acc[2] = __builtin_amdgcn_mfma_f32_16x16x32_bf16(xa[ks], bfrag[2][ks], acc[2], 0, 0, 0);
            }
#pragma unroll
            for (int tn = 0; tn < 3; ++tn)
                *reinterpret_cast<f32x4*>(&part[w * 768 + (tn * 16 + l16) * 16 + quad * 4]) = acc[tn];
            // prefetch x_{t+1} frags (hidden behind waves 4-7 latency)
            int tn_ = (t + 1 < T_STEPS) ? t + 1 : t;
            const unsigned short* src = insB + ((size_t)tn_ * BATCH + g * BT + l16) * HDIM;
#pragma unroll
            for (int ks = 0; ks < 4; ++ks)
                xa[ks] = *reinterpret_cast<const short8*>(src + w * 128 + ks * 32 + quad * 8);
        } else {
            // h-half: wave w needs only h-cols [(w-4)*128, +128) = blocks 8(w-4)..+8
            // FIX(v3): reference zeroes h BEFORE h@Wh -> mask the A-fragment.
            // Issue the rmask load before the spin so its latency hides.
            unsigned char rsta = rmask[t * BATCH + g * BT + l16];
            const int fidx = (w - 4) * 8 + (lane & 7);
            const int target = t + 1;
            int guard = 0;
            while (true) {
                int v = __hip_atomic_load(&flags[fidx], __ATOMIC_RELAXED, __HIP_MEMORY_SCOPE_AGENT);
                if (__ballot((lane >= 8) | (v >= target)) == ~0ull) break;
                if (++guard > (1 << 18)) break;   // failsafe vs hang (stale h would fail absmax)
            }
            asm volatile("" ::: "memory");
            const unsigned short* hb = (t & 1) ? hbuf1 : hbuf0;
            const unsigned long long* hb8 =
                (const unsigned long long*)(hb + (size_t)(g * BT + l16) * HDIM + (w - 4) * 128);
            unsigned long long hq[8];
#pragma unroll
            for (int ks = 0; ks < 4; ++ks) {
                int e = (ks * 32 + quad * 8) >> 2;   // ull index (4 bf16 each)
                hq[2 * ks]     = __hip_atomic_load(&hb8[e],     __ATOMIC_RELAXED, __HIP_MEMORY_SCOPE_AGENT);
                hq[2 * ks + 1] = __hip_atomic_load(&hb8[e + 1], __ATOMIC_RELAXED, __HIP_MEMORY_SCOPE_AGENT);
            }
            if (rsta) {
#pragma unroll
                for (int i = 0; i < 8; ++i) hq[i] = 0ull;   // h row resets to zero pre-matmul
            }
#pragma unroll
            for (int ks = 0; ks < 4; ++ks) {
                union { unsigned long long q[2]; short8 v; } af;
                af.q[0] = hq[2 * ks]; af.q[1] = hq[2 * ks + 1];
                acc[0] = __builtin_amdgcn_mfma_f32_16x16x32_bf16(af.v, bfrag[0][ks], acc[0], 0, 0, 0);
                acc[1] = __builtin_amdgcn_mfma_f32_16x16x32_bf16(af.v, bfrag[1][ks], acc[1], 0, 0, 0);
                acc[2] = __builtin_amdgcn_mfma_f32_16x16x32_bf16(af.v, bfrag[2][ks], acc[2], 0, 0, 0);
            }
#pragma unroll
            for (int tn = 0; tn < 3; ++tn)
                *reinterpret_cast<f32x4*>(&part[w * 768 + (tn * 16 + l16) * 16 + quad * 4]) = acc[tn];
        }
        __syncthreads();   // sync#1: all partials in LDS; block gated on all 32 flags

        if (tid < 256) {
            int m = tid & 15, u = tid >> 4;       // m-fast: part[] reads 2-way (free)
            float rs = 0.f, zs = 0.f, ni = 0.f, nh = 0.f;
#pragma unroll
            for (int ww = 0; ww < 8; ++ww) {
                rs += part[ww * 768 + u * 16 + m];
                zs += part[ww * 768 + (16 + u) * 16 + m];
                float p = part[ww * 768 + (32 + u) * 16 + m];
                if (ww < 4) ni += p; else nh += p;
            }
            float r = sigmoidf_(rs + bi_lds[u]);
            float z = sigmoidf_(zs + bi_lds[16 + u]);
            float n = tanhf_(ni + bi_lds[32 + u] + r * (nh + bhn_lds[u]));
            float hp = myrst ? 0.f : h_prev;
            float hv = (1.f - z) * n + z * hp;
            h_prev = hv;
            ys[((size_t)t * BATCH + g * BT + m) * HDIM + c0 + u] = hv;
            unsigned short* hbn = ((t + 1) & 1) ? hbuf1 : hbuf0;
            __hip_atomic_store(&hbn[(size_t)(g * BT + m) * HDIM + c0 + u], f2bf(hv),
                               __ATOMIC_RELAXED, __HIP_MEMORY_SCOPE_AGENT);
            asm volatile("s_waitcnt vmcnt(0)" ::: "memory");   // h patch acked at LLC
        }
        __syncthreads();   // sync#2: all 4 publisher waves drained
        if (tid == 0)
            __hip_atomic_store(&flags[cb], t + 2, __ATOMIC_RELAXED, __HIP_MEMORY_SCOPE_AGENT);
    }
}

extern "C" void kernel_launch(void* const* d_in, const int* in_sizes, int n_in,
                              void* d_out, int out_size, void* d_ws, size_t ws_size,
                              hipStream_t stream) {
    const float* ins    = (const float*)d_in[0];
    const void*  resets = d_in[1];
    const float* h0     = (const float*)d_in[2];
    const float* Wi     = (const float*)d_in[3];
    const float* Wh     = (const float*)d_in[4];
    const float* bi     = (const float*)d_in[5];
    const float* bhn    = (const float*)d_in[6];
    float* ys = (float*)d_out;
    char* ws = (char*)d_ws;

    unsigned short* insB  = (unsigned short*)(ws + OFF_INSB);
    unsigned short* WT    = (unsigned short*)(ws + OFF_WT);
    unsigned short* hbuf0 = (unsigned short*)(ws + OFF_HBUF0);
    unsigned short* hbuf1 = (unsigned short*)(ws + OFF_HBUF1);
    unsigned char*  rmask = (unsigned char*)(ws + OFF_RMASK);
    int*            flag  = (int*)(ws + OFF_FLAG);
    int*            flags = (int*)(ws + OFF_CNT);

    // flags + detector are re-poisoned 0xAA before every call -> zero each launch
    hipMemsetAsync(ws + OFF_FLAG, 0, 256 + CNT_BYTES, stream);

    k_detect<<<1, 256, 0, stream>>>((const unsigned int*)resets, flag);
    k_canon<<<256, 256, 0, stream>>>((const unsigned char*)resets, (const unsigned int*)resets, flag, rmask);
    k_cvt_ins<<<16384, 256, 0, stream>>>(ins, insB);
    k_build_wt<<<6144, 256, 0, stream>>>(Wi, Wh, WT);
    rnn_persist<<<NBLOCKS, THREADS, 0, stream>>>(h0, bi, bhn, rmask, insB, WT, hbuf0, hbuf1, flags, ys);
}